// Round 19
// baseline (29.751 us; speedup 1.0000x reference)
//
#include <hip/hip_runtime.h>

namespace {
constexpr int kB = 32, kT = 30, kD = 512, kL = 196;
constexpr float kK = 2.8853900817779268f;  // 2*log2(e)
constexpr size_t kGsz = (size_t)kB * kT * kL;  // 188,160

// vwi/u + vwj/v = (vwi*v + vwj*u) * rcp(u*v): 1 rcp per 2 elements
#define PAIR(ex, ey, fx, fy, vx, vy, acc)                                   \
  {                                                                         \
    const float u_ = fmaf(ex, fx, 1.f);                                     \
    const float v_ = fmaf(ey, fy, 1.f);                                     \
    acc = fmaf(fmaf(v_, vx, u_ * vy), __builtin_amdgcn_rcpf(u_ * v_), acc); \
  }

// g8[dqg][b][t][l] (l<192) = sum over 64 d of vw_d/(1+E*F).
// 768 blocks (bg:8 XCD-affine x bi:4 x lc:3 x dqg:8) x 512 thr (8 waves).
// Waves = (tg:4 t-groups x dh:2 d-halves); wave = 8t x 32d x 64l.
// R16-verified (best total 28.66us).
__global__ __launch_bounds__(512) void k_score(const float* __restrict__ x,
                                               const float* __restrict__ w,
                                               const float* __restrict__ img,
                                               const float* __restrict__ vw,
                                               float* __restrict__ g8) {
  __shared__ __align__(16) float4 Fl4[16 * 64];  // [c][l ^ (c&7)]  16 KB
  __shared__ __align__(16) float4 El4[32 * 16];  // [row][c4]        8 KB
  __shared__ __align__(16) float4 vwl4[16];      //                 256 B
  __shared__ __align__(16) float sc[4 * 8 * 64];  // dh-merge scratch 8 KB
  int n = blockIdx.x;
  const int bg = n & 7;
  int m = n >> 3;  // 96 = 4 bi * 3 lc * 8 dqg
  const int bi = m & 3; m >>= 2;
  const int lc = m % 3;
  const int dqg = m / 3;
  const int b = bg * 4 + bi;
  const int l0 = lc * 64, d0 = dqg * 64;
  const int tid = threadIdx.x;
#pragma unroll
  for (int k = 0; k < 2; ++k) {
    const int i = tid + k * 512;
    const int l = i >> 4, c = i & 15;
    const float4 v =
        *(const float4*)(img + ((size_t)(b * kL + l0 + l)) * kD + d0 + 4 * c);
    float4 o;
    o.x = __builtin_amdgcn_exp2f(kK * v.x);
    o.y = __builtin_amdgcn_exp2f(kK * v.y);
    o.z = __builtin_amdgcn_exp2f(kK * v.z);
    o.w = __builtin_amdgcn_exp2f(kK * v.w);
    Fl4[c * 64 + (l ^ (c & 7))] = o;
  }
  {
    const int row = tid >> 4, c4 = tid & 15;
    const int tc = (row < kT) ? row : kT - 1;
    const size_t gi = ((size_t)(b * kT + tc)) * kD + d0 + 4 * c4;
    const float4 xv = *(const float4*)(x + gi);
    const float4 wv4 = *(const float4*)(w + gi);
    float4 e;
    e.x = __builtin_amdgcn_exp2f(kK * (xv.x + wv4.x));
    e.y = __builtin_amdgcn_exp2f(kK * (xv.y + wv4.y));
    e.z = __builtin_amdgcn_exp2f(kK * (xv.z + wv4.z));
    e.w = __builtin_amdgcn_exp2f(kK * (xv.w + wv4.w));
    El4[row * 16 + c4] = e;
  }
  if (tid < 16) vwl4[tid] = *(const float4*)(vw + d0 + 4 * tid);
  __syncthreads();
  const int lane = tid & 63, wva = tid >> 6;
  const int tg = wva & 3, dh = wva >> 2;  // t-group, d-half
  const int r0 = tg * 8;
  const float4* Ew = &El4[r0 * 16];
  float acc[8];
#pragma unroll
  for (int tt = 0; tt < 8; ++tt) acc[tt] = 0.f;
#pragma unroll
  for (int s = 0; s < 8; ++s) {
    const int c4 = dh * 8 + s;                   // (c4 & 7) == s
    const float4 f = Fl4[c4 * 64 + (lane ^ s)];  // per-lane, swizzled
    const float4 vv = vwl4[c4];                  // uniform broadcast
#pragma unroll
    for (int tt = 0; tt < 8; ++tt) {
      const float4 E = Ew[tt * 16 + c4];  // uniform broadcast
      PAIR(E.x, E.y, f.x, f.y, vv.x, vv.y, acc[tt]);
      PAIR(E.z, E.w, f.z, f.w, vv.z, vv.w, acc[tt]);
    }
  }
  if (dh == 1) {
#pragma unroll
    for (int tt = 0; tt < 8; ++tt) sc[(tg * 8 + tt) * 64 + lane] = acc[tt];
  }
  __syncthreads();
  if (dh == 0) {
    float* gp =
        g8 + (size_t)dqg * kGsz + ((size_t)(b * kT + r0)) * kL + l0 + lane;
#pragma unroll
    for (int tt = 0; tt < 8; ++tt) {
      if (r0 + tt < kT) {
        gp[(size_t)tt * kL] = acc[tt] + sc[(tg * 8 + tt) * 64 + lane];
      }
    }
  }
}

// Fused softmax + context. 384 blocks (bg:8 x bi:4 x tg:6 x dh:2) x 512 thr.
// Phase 1: waves 0-4 each compute ONE softmax row (t = t0+wv) -> AL2[wv][l]
//   (no serial double-row; R16 had wave0 doing 2 rows at 256 thr).
// Phase 2: 8 waves = (lq:4 l-quarters x ds:2 128-d sub-slices), float2
//   lanes, 4-deep img dbuf; two-stage reduce via red[4][5][256].
__global__ __launch_bounds__(512) void k_ctxa(const float* __restrict__ g8,
                                              const float* __restrict__ x,
                                              const float* __restrict__ w,
                                              const float* __restrict__ img,
                                              const float* __restrict__ vw,
                                              float* __restrict__ out) {
  __shared__ float AL2[5][200];                   // 4 KB
  __shared__ __align__(16) float red[4][5][256];  // 20 KB
  int n = blockIdx.x;
  const int bg = n & 7;
  int m = n >> 3;  // 48 = 4 bi * 6 tg * 2 dh
  const int bi = m & 3; m >>= 2;
  const int tg = m % 6;
  const int dh = m / 6;
  const int b = bg * 4 + bi;
  const int t0 = tg * 5, d0 = dh * 256;
  const int tid = threadIdx.x;
  const int lane = tid & 63;
  const int wv = tid >> 6;
  // ---- phase 1: one softmax row per wave (waves 0..4; t <= 29 always) ----
  if (wv < 5) {
    const int t = t0 + wv;
    const int l4 = lane & 3, dc = lane >> 2;
    const float* ir = img + ((size_t)(b * kL + 192 + l4)) * kD + dc * 32;
    const float* xr = x + ((size_t)(b * kT + t)) * kD + dc * 32;
    const float* wr = w + ((size_t)(b * kT + t)) * kD + dc * 32;
    const float* vr = vw + dc * 32;
    float tgv = 0.f;
#pragma unroll
    for (int k = 0; k < 8; ++k) {
      const float4 iv = *(const float4*)(ir + 4 * k);
      const float4 xv = *(const float4*)(xr + 4 * k);
      const float4 wv4 = *(const float4*)(wr + 4 * k);
      const float4 vv = *(const float4*)(vr + 4 * k);
      const float fx = __builtin_amdgcn_exp2f(kK * iv.x);
      const float fy = __builtin_amdgcn_exp2f(kK * iv.y);
      const float fz = __builtin_amdgcn_exp2f(kK * iv.z);
      const float fw = __builtin_amdgcn_exp2f(kK * iv.w);
      const float ex = __builtin_amdgcn_exp2f(kK * (xv.x + wv4.x));
      const float ey = __builtin_amdgcn_exp2f(kK * (xv.y + wv4.y));
      const float ez = __builtin_amdgcn_exp2f(kK * (xv.z + wv4.z));
      const float ew = __builtin_amdgcn_exp2f(kK * (xv.w + wv4.w));
      PAIR(ex, ey, fx, fy, vv.x, vv.y, tgv);
      PAIR(ez, ew, fz, fw, vv.z, vv.w, tgv);
    }
#pragma unroll
    for (int s2 = 4; s2 < 64; s2 <<= 1) tgv += __shfl_xor(tgv, s2, 64);
    const size_t base = ((size_t)(b * kT + t)) * kL;
    float q0 = 0.f, q1 = 0.f, q2 = 0.f;
#pragma unroll
    for (int p = 0; p < 8; ++p) {
      const float* gp = g8 + (size_t)p * kGsz + base;
      q0 += gp[lane];
      q1 += gp[lane + 64];
      q2 += gp[lane + 128];
    }
    q0 *= kK; q1 *= kK; q2 *= kK;
    float q3 = (lane < 4) ? tgv * kK : __builtin_inff();
    float mn = fminf(fminf(q0, q1), fminf(q2, q3));
#pragma unroll
    for (int s2 = 1; s2 < 64; s2 <<= 1) mn = fminf(mn, __shfl_xor(mn, s2, 64));
    const float e0 = __builtin_amdgcn_exp2f(mn - q0);
    const float e1 = __builtin_amdgcn_exp2f(mn - q1);
    const float e2 = __builtin_amdgcn_exp2f(mn - q2);
    const float e3 = (lane < 4) ? __builtin_amdgcn_exp2f(mn - q3) : 0.f;
    float s = e0 + e1 + e2 + e3;
#pragma unroll
    for (int s2 = 1; s2 < 64; s2 <<= 1) s += __shfl_xor(s, s2, 64);
    const float rs = __builtin_amdgcn_rcpf(s);
    AL2[wv][lane] = e0 * rs;
    AL2[wv][lane + 64] = e1 * rs;
    AL2[wv][lane + 128] = e2 * rs;
    if (lane < 4) AL2[wv][lane + 192] = e3 * rs;
  }
  __syncthreads();
  // ---- phase 2: context GEMV; wave = (lq l-quarter, ds 128-d slice) ----
  {
    const int lq = __builtin_amdgcn_readfirstlane(wv & 3);
    const int ds = __builtin_amdgcn_readfirstlane(wv >> 2);
    const int lb = lq * 49;
    const float* ip =
        img + ((size_t)(b * kL + lb)) * kD + d0 + ds * 128 + 2 * lane;
    float2 a0 = {0.f, 0.f}, a1 = {0.f, 0.f}, a2 = {0.f, 0.f},
           a3 = {0.f, 0.f}, a4 = {0.f, 0.f};
    float2 fA[4], fB[4];
    auto loadI = [&](float2* f, int bb) {
#pragma unroll
      for (int j = 0; j < 4; ++j)
        f[j] = *(const float2*)(ip + (size_t)(bb * 4 + j) * kD);
    };
    auto compI = [&](const float2* f, int bb) {
#pragma unroll
      for (int j = 0; j < 4; ++j) {
        const int l = lb + bb * 4 + j;
        const float w0 = AL2[0][l];  // uniform broadcasts (conflict-free)
        const float w1 = AL2[1][l];
        const float w2 = AL2[2][l];
        const float w3 = AL2[3][l];
        const float w4 = AL2[4][l];
        a0.x = fmaf(f[j].x, w0, a0.x); a0.y = fmaf(f[j].y, w0, a0.y);
        a1.x = fmaf(f[j].x, w1, a1.x); a1.y = fmaf(f[j].y, w1, a1.y);
        a2.x = fmaf(f[j].x, w2, a2.x); a2.y = fmaf(f[j].y, w2, a2.y);
        a3.x = fmaf(f[j].x, w3, a3.x); a3.y = fmaf(f[j].y, w3, a3.y);
        a4.x = fmaf(f[j].x, w4, a4.x); a4.y = fmaf(f[j].y, w4, a4.y);
      }
    };
    loadI(fA, 0);
#pragma unroll
    for (int bb = 0; bb < 12; ++bb) {
      if (bb + 1 < 12) {
        if ((bb + 1) & 1) loadI(fB, bb + 1);
        else loadI(fA, bb + 1);
      }
      if (bb & 1) compI(fB, bb);
      else compI(fA, bb);
    }
    {  // tail l-index 48 of this quarter
      const float2 v = *(const float2*)(ip + (size_t)48 * kD);
      const int l = lb + 48;
      const float w0 = AL2[0][l], w1 = AL2[1][l], w2 = AL2[2][l],
                  w3 = AL2[3][l], w4 = AL2[4][l];
      a0.x = fmaf(v.x, w0, a0.x); a0.y = fmaf(v.y, w0, a0.y);
      a1.x = fmaf(v.x, w1, a1.x); a1.y = fmaf(v.y, w1, a1.y);
      a2.x = fmaf(v.x, w2, a2.x); a2.y = fmaf(v.y, w2, a2.y);
      a3.x = fmaf(v.x, w3, a3.x); a3.y = fmaf(v.y, w3, a3.y);
      a4.x = fmaf(v.x, w4, a4.x); a4.y = fmaf(v.y, w4, a4.y);
    }
    const int co = ds * 128 + 2 * lane;
    *(float2*)&red[lq][0][co] = a0;
    *(float2*)&red[lq][1][co] = a1;
    *(float2*)&red[lq][2][co] = a2;
    *(float2*)&red[lq][3][co] = a3;
    *(float2*)&red[lq][4][co] = a4;
  }
  __syncthreads();
  // reduce 4 l-quarters; 1280 outputs / 512 thr = up to 3 each
#pragma unroll
  for (int k = 0; k < 3; ++k) {
    const int idx = tid + k * 512;
    if (idx < 1280) {
      const int j = idx >> 8, col = idx & 255;
      const float s =
          red[0][j][col] + red[1][j][col] + red[2][j][col] + red[3][j][col];
      out[((size_t)(b * kT + t0 + j)) * kD + d0 + col] = s;
    }
  }
}
}  // namespace

extern "C" void kernel_launch(void* const* d_in, const int* in_sizes, int n_in,
                              void* d_out, int out_size, void* d_ws, size_t ws_size,
                              hipStream_t stream) {
  const float* x = (const float*)d_in[0];
  const float* wordemb = (const float*)d_in[1];
  const float* img = (const float*)d_in[2];
  const float* vw = (const float*)d_in[3];
  // v_b (d_in[4]) cancels in the softmax along with sum(v_w) — unused by design.
  float* out = (float*)d_out;
  float* g8 = (float*)d_ws;  // 8 * 188,160 floats = 6.02 MB
  hipLaunchKernelGGL(k_score, dim3(768), dim3(512), 0, stream, x, wordemb, img,
                     vw, g8);
  hipLaunchKernelGGL(k_ctxa, dim3(384), dim3(512), 0, stream, g8, x, wordemb,
                     img, vw, out);
}

// Round 20
// 28.765 us; speedup vs baseline: 1.0343x; 1.0343x over previous
//
#include <hip/hip_runtime.h>

namespace {
constexpr int kB = 32, kT = 30, kD = 512, kL = 196;
constexpr float kK = 2.8853900817779268f;  // 2*log2(e)
constexpr size_t kGsz = (size_t)kB * kT * kL;  // 188,160

// vwi/u + vwj/v = (vwi*v + vwj*u) * rcp(u*v): 1 rcp per 2 elements
#define PAIR(ex, ey, fx, fy, vx, vy, acc)                                   \
  {                                                                         \
    const float u_ = fmaf(ex, fx, 1.f);                                     \
    const float v_ = fmaf(ey, fy, 1.f);                                     \
    acc = fmaf(fmaf(v_, vx, u_ * vy), __builtin_amdgcn_rcpf(u_ * v_), acc); \
  }

// g8[dqg][b][t][l] (l<192) = sum over 64 d of vw_d/(1+E*F).
// 768 blocks (bg:8 XCD-affine x bi:4 x lc:3 x dqg:8) x 512 thr (8 waves).
// Waves = (tg:4 t-groups x dh:2 d-halves); wave = 8t x 32d x 64l.
// R16-verified (best total 28.66us).
__global__ __launch_bounds__(512) void k_score(const float* __restrict__ x,
                                               const float* __restrict__ w,
                                               const float* __restrict__ img,
                                               const float* __restrict__ vw,
                                               float* __restrict__ g8) {
  __shared__ __align__(16) float4 Fl4[16 * 64];  // [c][l ^ (c&7)]  16 KB
  __shared__ __align__(16) float4 El4[32 * 16];  // [row][c4]        8 KB
  __shared__ __align__(16) float4 vwl4[16];      //                 256 B
  __shared__ __align__(16) float sc[4 * 8 * 64];  // dh-merge scratch 8 KB
  int n = blockIdx.x;
  const int bg = n & 7;
  int m = n >> 3;  // 96 = 4 bi * 3 lc * 8 dqg
  const int bi = m & 3; m >>= 2;
  const int lc = m % 3;
  const int dqg = m / 3;
  const int b = bg * 4 + bi;
  const int l0 = lc * 64, d0 = dqg * 64;
  const int tid = threadIdx.x;
#pragma unroll
  for (int k = 0; k < 2; ++k) {
    const int i = tid + k * 512;
    const int l = i >> 4, c = i & 15;
    const float4 v =
        *(const float4*)(img + ((size_t)(b * kL + l0 + l)) * kD + d0 + 4 * c);
    float4 o;
    o.x = __builtin_amdgcn_exp2f(kK * v.x);
    o.y = __builtin_amdgcn_exp2f(kK * v.y);
    o.z = __builtin_amdgcn_exp2f(kK * v.z);
    o.w = __builtin_amdgcn_exp2f(kK * v.w);
    Fl4[c * 64 + (l ^ (c & 7))] = o;
  }
  {
    const int row = tid >> 4, c4 = tid & 15;
    const int tc = (row < kT) ? row : kT - 1;
    const size_t gi = ((size_t)(b * kT + tc)) * kD + d0 + 4 * c4;
    const float4 xv = *(const float4*)(x + gi);
    const float4 wv4 = *(const float4*)(w + gi);
    float4 e;
    e.x = __builtin_amdgcn_exp2f(kK * (xv.x + wv4.x));
    e.y = __builtin_amdgcn_exp2f(kK * (xv.y + wv4.y));
    e.z = __builtin_amdgcn_exp2f(kK * (xv.z + wv4.z));
    e.w = __builtin_amdgcn_exp2f(kK * (xv.w + wv4.w));
    El4[row * 16 + c4] = e;
  }
  if (tid < 16) vwl4[tid] = *(const float4*)(vw + d0 + 4 * tid);
  __syncthreads();
  const int lane = tid & 63, wva = tid >> 6;
  const int tg = wva & 3, dh = wva >> 2;  // t-group, d-half
  const int r0 = tg * 8;
  const float4* Ew = &El4[r0 * 16];
  float acc[8];
#pragma unroll
  for (int tt = 0; tt < 8; ++tt) acc[tt] = 0.f;
#pragma unroll
  for (int s = 0; s < 8; ++s) {
    const int c4 = dh * 8 + s;                   // (c4 & 7) == s
    const float4 f = Fl4[c4 * 64 + (lane ^ s)];  // per-lane, swizzled
    const float4 vv = vwl4[c4];                  // uniform broadcast
#pragma unroll
    for (int tt = 0; tt < 8; ++tt) {
      const float4 E = Ew[tt * 16 + c4];  // uniform broadcast
      PAIR(E.x, E.y, f.x, f.y, vv.x, vv.y, acc[tt]);
      PAIR(E.z, E.w, f.z, f.w, vv.z, vv.w, acc[tt]);
    }
  }
  if (dh == 1) {
#pragma unroll
    for (int tt = 0; tt < 8; ++tt) sc[(tg * 8 + tt) * 64 + lane] = acc[tt];
  }
  __syncthreads();
  if (dh == 0) {
    float* gp =
        g8 + (size_t)dqg * kGsz + ((size_t)(b * kT + r0)) * kL + l0 + lane;
#pragma unroll
    for (int tt = 0; tt < 8; ++tt) {
      if (r0 + tt < kT) {
        gp[(size_t)tt * kL] = acc[tt] + sc[(tg * 8 + tt) * 64 + lane];
      }
    }
  }
}

// Fused softmax + context. Grid identical to R13 k_ctx (384, XCD-affine).
// Phase 1: 4 waves compute softmax rows r=wv (+ wv==0: r=4) -> AL2[r][l]
//   (#pragma unroll 1: one softmax body live at a time — R12 spill fix #1).
// Phase 2: R13 ctx with 4-deep dbuf (spill fix #2) + AL2 broadcast reads.
__global__ __launch_bounds__(256) void k_ctxa(const float* __restrict__ g8,
                                              const float* __restrict__ x,
                                              const float* __restrict__ w,
                                              const float* __restrict__ img,
                                              const float* __restrict__ vw,
                                              float* __restrict__ out) {
  __shared__ float AL2[5][200];                   // 4 KB; writes lane-consec
  __shared__ __align__(16) float red[4][5][256];  // 20 KB
  int n = blockIdx.x;
  const int bg = n & 7;
  int m = n >> 3;  // 48 = 4 bi * 6 tg * 2 dh
  const int bi = m & 3; m >>= 2;
  const int tg = m % 6;
  const int dh = m / 6;
  const int b = bg * 4 + bi;
  const int t0 = tg * 5, d0 = dh * 256;
  const int tid = threadIdx.x;
  const int lane = tid & 63;
  const int wv = tid >> 6;
  // ---- phase 1: softmax rows (t = t0 + r <= 29 always) ----
#pragma unroll 1
  for (int r = wv; r < 5; r += 4) {
    const int t = t0 + r;
    const int l4 = lane & 3, dc = lane >> 2;
    const float* ir = img + ((size_t)(b * kL + 192 + l4)) * kD + dc * 32;
    const float* xr = x + ((size_t)(b * kT + t)) * kD + dc * 32;
    const float* wr = w + ((size_t)(b * kT + t)) * kD + dc * 32;
    const float* vr = vw + dc * 32;
    float tgv = 0.f;
#pragma unroll
    for (int k = 0; k < 8; ++k) {
      const float4 iv = *(const float4*)(ir + 4 * k);
      const float4 xv = *(const float4*)(xr + 4 * k);
      const float4 wv4 = *(const float4*)(wr + 4 * k);
      const float4 vv = *(const float4*)(vr + 4 * k);
      const float fx = __builtin_amdgcn_exp2f(kK * iv.x);
      const float fy = __builtin_amdgcn_exp2f(kK * iv.y);
      const float fz = __builtin_amdgcn_exp2f(kK * iv.z);
      const float fw = __builtin_amdgcn_exp2f(kK * iv.w);
      const float ex = __builtin_amdgcn_exp2f(kK * (xv.x + wv4.x));
      const float ey = __builtin_amdgcn_exp2f(kK * (xv.y + wv4.y));
      const float ez = __builtin_amdgcn_exp2f(kK * (xv.z + wv4.z));
      const float ew = __builtin_amdgcn_exp2f(kK * (xv.w + wv4.w));
      PAIR(ex, ey, fx, fy, vv.x, vv.y, tgv);
      PAIR(ez, ew, fz, fw, vv.z, vv.w, tgv);
    }
#pragma unroll
    for (int mm = 4; mm < 64; mm <<= 1) tgv += __shfl_xor(tgv, mm, 64);
    const size_t base = ((size_t)(b * kT + t)) * kL;
    float q0 = 0.f, q1 = 0.f, q2 = 0.f;
#pragma unroll
    for (int p = 0; p < 8; ++p) {
      const float* gp = g8 + (size_t)p * kGsz + base;
      q0 += gp[lane];
      q1 += gp[lane + 64];
      q2 += gp[lane + 128];
    }
    q0 *= kK; q1 *= kK; q2 *= kK;
    float q3 = (lane < 4) ? tgv * kK : __builtin_inff();
    float mn = fminf(fminf(q0, q1), fminf(q2, q3));
#pragma unroll
    for (int mm = 1; mm < 64; mm <<= 1) mn = fminf(mn, __shfl_xor(mn, mm, 64));
    const float e0 = __builtin_amdgcn_exp2f(mn - q0);
    const float e1 = __builtin_amdgcn_exp2f(mn - q1);
    const float e2 = __builtin_amdgcn_exp2f(mn - q2);
    const float e3 = (lane < 4) ? __builtin_amdgcn_exp2f(mn - q3) : 0.f;
    float s = e0 + e1 + e2 + e3;
#pragma unroll
    for (int mm = 1; mm < 64; mm <<= 1) s += __shfl_xor(s, mm, 64);
    const float rs = __builtin_amdgcn_rcpf(s);
    AL2[r][lane] = e0 * rs;
    AL2[r][lane + 64] = e1 * rs;
    AL2[r][lane + 128] = e2 * rs;
    if (lane < 4) AL2[r][lane + 192] = e3 * rs;
  }
  __syncthreads();
  // ---- phase 2: context GEMV (R13 structure, 4-deep dbuf) ----
  const int lru = __builtin_amdgcn_readfirstlane(wv);  // wave's l-quarter
  const float* ip = img + ((size_t)(b * kL + lru * 49)) * kD + d0 + 4 * lane;
  const int lb = lru * 49;
  float4 acc[5];
#pragma unroll
  for (int j = 0; j < 5; ++j) acc[j] = {0.f, 0.f, 0.f, 0.f};
  auto loadI = [&](float4* dst, int bb) {
#pragma unroll
    for (int j = 0; j < 4; ++j)
      dst[j] = *(const float4*)(ip + (size_t)(bb * 4 + j) * kD);
  };
  auto compI = [&](const float4* f, int bb) {
#pragma unroll
    for (int j = 0; j < 4; ++j) {
      const int l = lb + bb * 4 + j;
      const float a0 = AL2[0][l];  // uniform broadcasts (conflict-free)
      const float a1 = AL2[1][l];
      const float a2 = AL2[2][l];
      const float a3 = AL2[3][l];
      const float a4 = AL2[4][l];
      acc[0].x = fmaf(f[j].x, a0, acc[0].x); acc[0].y = fmaf(f[j].y, a0, acc[0].y);
      acc[0].z = fmaf(f[j].z, a0, acc[0].z); acc[0].w = fmaf(f[j].w, a0, acc[0].w);
      acc[1].x = fmaf(f[j].x, a1, acc[1].x); acc[1].y = fmaf(f[j].y, a1, acc[1].y);
      acc[1].z = fmaf(f[j].z, a1, acc[1].z); acc[1].w = fmaf(f[j].w, a1, acc[1].w);
      acc[2].x = fmaf(f[j].x, a2, acc[2].x); acc[2].y = fmaf(f[j].y, a2, acc[2].y);
      acc[2].z = fmaf(f[j].z, a2, acc[2].z); acc[2].w = fmaf(f[j].w, a2, acc[2].w);
      acc[3].x = fmaf(f[j].x, a3, acc[3].x); acc[3].y = fmaf(f[j].y, a3, acc[3].y);
      acc[3].z = fmaf(f[j].z, a3, acc[3].z); acc[3].w = fmaf(f[j].w, a3, acc[3].w);
      acc[4].x = fmaf(f[j].x, a4, acc[4].x); acc[4].y = fmaf(f[j].y, a4, acc[4].y);
      acc[4].z = fmaf(f[j].z, a4, acc[4].z); acc[4].w = fmaf(f[j].w, a4, acc[4].w);
    }
  };
  float4 fA[4], fB[4];
  loadI(fA, 0);
#pragma unroll
  for (int bb = 0; bb < 12; ++bb) {
    if (bb + 1 < 12) {
      if ((bb + 1) & 1) loadI(fB, bb + 1);
      else loadI(fA, bb + 1);
    }
    if (bb & 1) compI(fB, bb);
    else compI(fA, bb);
  }
  {  // tail l-index 48 of this quarter
    const float4 v = *(const float4*)(ip + (size_t)48 * kD);
    const int l = lb + 48;
    const float a0 = AL2[0][l], a1 = AL2[1][l], a2 = AL2[2][l],
                a3 = AL2[3][l], a4 = AL2[4][l];
    acc[0].x = fmaf(v.x, a0, acc[0].x); acc[0].y = fmaf(v.y, a0, acc[0].y);
    acc[0].z = fmaf(v.z, a0, acc[0].z); acc[0].w = fmaf(v.w, a0, acc[0].w);
    acc[1].x = fmaf(v.x, a1, acc[1].x); acc[1].y = fmaf(v.y, a1, acc[1].y);
    acc[1].z = fmaf(v.z, a1, acc[1].z); acc[1].w = fmaf(v.w, a1, acc[1].w);
    acc[2].x = fmaf(v.x, a2, acc[2].x); acc[2].y = fmaf(v.y, a2, acc[2].y);
    acc[2].z = fmaf(v.z, a2, acc[2].z); acc[2].w = fmaf(v.w, a2, acc[2].w);
    acc[3].x = fmaf(v.x, a3, acc[3].x); acc[3].y = fmaf(v.y, a3, acc[3].y);
    acc[3].z = fmaf(v.z, a3, acc[3].z); acc[3].w = fmaf(v.w, a3, acc[3].w);
    acc[4].x = fmaf(v.x, a4, acc[4].x); acc[4].y = fmaf(v.y, a4, acc[4].y);
    acc[4].z = fmaf(v.z, a4, acc[4].z); acc[4].w = fmaf(v.w, a4, acc[4].w);
  }
#pragma unroll
  for (int j = 0; j < 5; ++j) *(float4*)&red[wv][j][4 * lane] = acc[j];
  __syncthreads();
#pragma unroll
  for (int j = 0; j < 5; ++j) {
    const float s =
        red[0][j][tid] + red[1][j][tid] + red[2][j][tid] + red[3][j][tid];
    out[((size_t)(b * kT + t0 + j)) * kD + d0 + tid] = s;
  }
}
}  // namespace

extern "C" void kernel_launch(void* const* d_in, const int* in_sizes, int n_in,
                              void* d_out, int out_size, void* d_ws, size_t ws_size,
                              hipStream_t stream) {
  const float* x = (const float*)d_in[0];
  const float* wordemb = (const float*)d_in[1];
  const float* img = (const float*)d_in[2];
  const float* vw = (const float*)d_in[3];
  // v_b (d_in[4]) cancels in the softmax along with sum(v_w) — unused by design.
  float* out = (float*)d_out;
  float* g8 = (float*)d_ws;  // 6.02 MB
  hipLaunchKernelGGL(k_score, dim3(768), dim3(512), 0, stream, x, wordemb, img,
                     vw, g8);
  hipLaunchKernelGGL(k_ctxa, dim3(384), dim3(256), 0, stream, g8, x, wordemb,
                     img, vw, out);
}